// Round 8
// baseline (89.191 us; speedup 1.0000x reference)
//
#include <hip/hip_runtime.h>
#include <hip/hip_bf16.h>

#define N_DIM   3072
#define BATCH_N 8192
#define K_FIX   30

typedef __attribute__((ext_vector_type(8)))  short short8v;   // 8 bf16
typedef __attribute__((ext_vector_type(16))) float f32x16;

static __device__ __forceinline__ short bfs(float f) {
    __hip_bfloat16 h = __float2bfloat16(f);       // RNE; compiler pairs into
    return __builtin_bit_cast(short, h);          // v_cvt_pk_bf16_f32 (m240)
}

static __device__ __forceinline__ short8v pack8(const float4 a, const float4 b) {
    short8v r;
    r[0] = bfs(a.x); r[1] = bfs(a.y); r[2] = bfs(a.z); r[3] = bfs(a.w);
    r[4] = bfs(b.x); r[5] = bfs(b.y); r[6] = bfs(b.z); r[7] = bfs(b.w);
    return r;
}

// ---------------- Path 1: max-TLP barrier-free MFMA band-GEMM ---------------
// out[b, r] = sum_i x[b, r-i] * V[i, r-i].  ONE 32x32 output tile per wave:
// D[32x32] = A[32x64] x B[64x32] via 4 x mfma_f32_32x32x16_bf16, where
// A[row][k] = x[b0+row, (cg0-32+k) mod N], B[k][j] = V[i][...], i = j+32-k.
// 24576 independent waves (96 col-groups x 256 row-groups) ~= 8 waves/SIMD
// x 3 rounds: memory latency is hidden by TLP, not ILP -- R7 showed the
// allocator (VGPR=52) serializes in-wave load chains, and 3 waves/SIMD
// couldn't cover them.  No LDS, no barriers.
// C/D layout (m74/m101): col = lane&31, row = (reg&3) + 8*(reg>>2) + 4*(lane>>5)
#define CG     32
#define NCG    (N_DIM / CG)          // 96 col groups
#define NRG    (BATCH_N / 32)        // 256 row groups (32 rows per wave)

__global__ __launch_bounds__(256)
void fc_diag_mfma32(const float* __restrict__ x, const float* __restrict__ V,
                    const int* __restrict__ dp, float* __restrict__ out)
{
    bool ok = true;
    #pragma unroll
    for (int i = 0; i < K_FIX; ++i) ok = ok && (dp[i] == i);
    if (!ok) return;

    const int lane = (int)threadIdx.x & 63;
    const int gw   = (int)blockIdx.x * 4 + ((int)threadIdx.x >> 6);
    const int cgi  = gw % NCG;        // block's 4 waves: adjacent col groups,
    const int rgi  = gw / NCG;        // same rows (4 | 96 -> never straddles)
    const int cg0  = cgi * CG;
    const int b0   = rgi * 32;
    const int j    = lane & 31;       // col within group / B col / A row
    const int hi   = lane >> 5;

    // ---- B fragments (band of W^T), 16 VGPR ----
    // Bf[step][jj]: k = 16*step + hi*8 + jj, i = j + 32 - k, B=V[i][cg0-32+k].
    short8v Bf[4];
    #pragma unroll
    for (int step = 0; step < 4; ++step) {
        #pragma unroll
        for (int jj = 0; jj < 8; ++jj) {
            const int k = 16 * step + hi * 8 + jj;
            const int i = j + 32 - k;
            short v = 0;
            if (i >= 0 && i < K_FIX) {
                int c = cg0 - 32 + k;
                if (c < 0) c += N_DIM;
                v = bfs(V[(size_t)i * N_DIM + c]);
            }
            Bf[step][jj] = v;
        }
    }

    // ---- A tile: 8 independent float4 loads (row-contiguous per lane) ----
    // kbase multiple of 8, N_DIM multiple of 8 -> segments 16B-aligned, no
    // mid-segment wrap.
    const int kbase = cg0 - 32 + hi * 8;
    const float* xr = x + (size_t)(b0 + j) * N_DIM;

    float4 la[4][2];
    #pragma unroll
    for (int step = 0; step < 4; ++step) {
        int c = kbase + 16 * step;
        if (c < 0) c += N_DIM;
        la[step][0] = *reinterpret_cast<const float4*>(xr + c);
        la[step][1] = *reinterpret_cast<const float4*>(xr + c + 4);
    }

    f32x16 acc = {0.f,0.f,0.f,0.f, 0.f,0.f,0.f,0.f,
                  0.f,0.f,0.f,0.f, 0.f,0.f,0.f,0.f};
    #pragma unroll
    for (int step = 0; step < 4; ++step) {
        const short8v a = pack8(la[step][0], la[step][1]);
        acc = __builtin_amdgcn_mfma_f32_32x32x16_bf16(a, Bf[step], acc, 0, 0, 0);
    }

    // ---- store: col = j, row = (reg&3) + 8*(reg>>2) + 4*hi ----
    float* ob = out + (size_t)b0 * N_DIM + cg0 + j;
    #pragma unroll
    for (int reg = 0; reg < 16; ++reg) {
        const int row = (reg & 3) + 8 * (reg >> 2) + 4 * hi;
        ob[(size_t)row * N_DIM] = acc[reg];
    }
}

// ---------------- Path 2: general K=30 (arbitrary diag values) --------------
#define G_NBT   128
#define G_BROWS (BATCH_N / G_NBT)    // 64

__global__ __launch_bounds__(256)
void fc_diag_general30(const float* __restrict__ x, const float* __restrict__ V,
                       const int* __restrict__ dp, float* __restrict__ out)
{
    bool contig = true;
    #pragma unroll
    for (int i = 0; i < K_FIX; ++i) contig = contig && (dp[i] == i);
    if (contig) return;  // fast kernel handled it

    const int NRT2 = N_DIM / 256;
    const int rtile = blockIdx.x % NRT2;
    const int btile = blockIdx.x / NRT2;
    const int r  = rtile * 256 + (int)threadIdx.x;
    const int b0 = btile * G_BROWS;

    int   CI[K_FIX];
    float VW[K_FIX];
    #pragma unroll
    for (int i = 0; i < K_FIX; ++i) {
        int d = dp[i] % N_DIM; if (d < 0) d += N_DIM;
        int c = r - d; if (c < 0) c += N_DIM;
        CI[i] = c;
        VW[i] = V[(size_t)d * N_DIM + c];
    }

    for (int b = b0; b < b0 + G_BROWS; b += 2) {
        const float* xb0 = x + (size_t)b * N_DIM;
        const float* xb1 = xb0 + N_DIM;
        float a0 = 0.f, a1 = 0.f;
        #pragma unroll
        for (int i = 0; i < K_FIX; ++i) {
            const float w = VW[i]; const int c = CI[i];
            a0 = fmaf(xb0[c], w, a0);
            a1 = fmaf(xb1[c], w, a1);
        }
        out[(size_t)b * N_DIM + r]       = a0;
        out[(size_t)(b + 1) * N_DIM + r] = a1;
    }
}

// ---------------- Path 3: naive fallback for K != 30 ------------------------
__global__ void fc_diag_naive(const float* __restrict__ x, const float* __restrict__ V,
                              const int* __restrict__ dp, int K, float* __restrict__ out)
{
    size_t idx   = (size_t)blockIdx.x * blockDim.x + threadIdx.x;
    size_t total = (size_t)BATCH_N * N_DIM;
    size_t step  = (size_t)gridDim.x * blockDim.x;
    for (; idx < total; idx += step) {
        int b = (int)(idx / N_DIM), r = (int)(idx % N_DIM);
        float acc = 0.f;
        for (int i = 0; i < K; ++i) {
            int d = dp[i] % N_DIM; if (d < 0) d += N_DIM;
            int c = r - d; if (c < 0) c += N_DIM;
            acc = fmaf(x[(size_t)b * N_DIM + c], V[(size_t)d * N_DIM + c], acc);
        }
        out[idx] = acc;
    }
}

extern "C" void kernel_launch(void* const* d_in, const int* in_sizes, int n_in,
                              void* d_out, int out_size, void* d_ws, size_t ws_size,
                              hipStream_t stream)
{
    const float* x  = (const float*)d_in[0];
    const float* V  = (const float*)d_in[1];
    const int*   dp = (const int*)d_in[2];
    float* out = (float*)d_out;
    const int K = in_sizes[2];

    if (K == K_FIX) {
        // 24576 waves = 96 col-groups x 256 row-groups; 4 waves/block
        fc_diag_mfma32<<<dim3(NCG * NRG / 4), dim3(256), 0, stream>>>(x, V, dp, out);
        fc_diag_general30<<<dim3((N_DIM / 256) * G_NBT), dim3(256), 0, stream>>>(x, V, dp, out);
    } else {
        fc_diag_naive<<<dim3(2048), dim3(256), 0, stream>>>(x, V, dp, K, out);
    }
}

// Round 9
// 54.086 us; speedup vs baseline: 1.6490x; 1.6490x over previous
//
#include <hip/hip_runtime.h>
#include <hip/hip_bf16.h>

#define N_DIM   3072
#define BATCH_N 8192
#define K_FIX   30

typedef __attribute__((ext_vector_type(8)))  short short8v;   // 8 bf16
typedef __attribute__((ext_vector_type(16))) float f32x16;

#define CG     32
#define NCG    (N_DIM / CG)          // 96 col groups
#define NRG    (BATCH_N / 32)        // 256 row groups (32 rows per wave)
#define BTAB_BYTES (NCG * 4 * 64 * sizeof(short8v))   // 393,216 B

static __device__ __forceinline__ short bfs(float f) {
    __hip_bfloat16 h = __float2bfloat16(f);       // RNE; compiler pairs into
    return __builtin_bit_cast(short, h);          // v_cvt_pk_bf16_f32 (m240)
}

static __device__ __forceinline__ short8v pack8(const float4 a, const float4 b) {
    short8v r;
    r[0] = bfs(a.x); r[1] = bfs(a.y); r[2] = bfs(a.z); r[3] = bfs(a.w);
    r[4] = bfs(b.x); r[5] = bfs(b.y); r[6] = bfs(b.z); r[7] = bfs(b.w);
    return r;
}

// ---- B-fragment build (band of W^T), shared by pre-kernel and fallback ----
// Bf[step][jj]: k = 16*step + hi*8 + jj, i = j + 32 - k, B = V[i][cg0-32+k].
static __device__ __forceinline__ short8v build_bfrag(
    const float* __restrict__ V, int cg0, int j, int hi, int step)
{
    short8v v8;
    #pragma unroll
    for (int jj = 0; jj < 8; ++jj) {
        const int k = 16 * step + hi * 8 + jj;
        const int i = j + 32 - k;
        short v = 0;
        if (i >= 0 && i < K_FIX) {
            int c = cg0 - 32 + k;
            if (c < 0) c += N_DIM;
            v = bfs(V[(size_t)i * N_DIM + c]);
        }
        v8[jj] = v;
    }
    return v8;
}

// ---------------- pre-kernel: materialize B-fragment table into d_ws --------
// btab[(cgi*4 + step)*64 + lane] -> per-step loads are lane-contiguous 16B
// (1 KiB per wave instruction).  96 waves total; runs in ~2 us.
__global__ __launch_bounds__(64)
void build_btab(const float* __restrict__ V, const int* __restrict__ dp,
                short8v* __restrict__ btab)
{
    bool ok = true;
    #pragma unroll
    for (int i = 0; i < K_FIX; ++i) ok = ok && (dp[i] == i);
    if (!ok) return;

    const int cgi  = (int)blockIdx.x;
    const int lane = (int)threadIdx.x;
    const int j    = lane & 31;
    const int hi   = lane >> 5;
    const int cg0  = cgi * CG;
    #pragma unroll
    for (int step = 0; step < 4; ++step)
        btab[(cgi * 4 + step) * 64 + lane] = build_bfrag(V, cg0, j, hi, step);
}

// ---------------- Path 1: max-TLP barrier-free MFMA band-GEMM ---------------
// ONE 32x32 output tile per wave: D = A[32x64] x B[64x32] via 4 x
// mfma_f32_32x32x16_bf16.  B comes from the precomputed table (4 coalesced
// 16B loads, L2-resident) -- R8 showed per-wave scattered B-build from V is
// the dominant cost at this wave count.  12 independent VMEM loads issued
// up-front; 24576 waves (~8/SIMD) hide the latency by TLP.  No LDS/barriers.
// C/D layout (m74/m101): col = lane&31, row = (reg&3)+8*(reg>>2)+4*(lane>>5).
template<bool USE_TAB>
__global__ __launch_bounds__(256)
void fc_diag_mfma32(const float* __restrict__ x, const float* __restrict__ V,
                    const int* __restrict__ dp, const short8v* __restrict__ btab,
                    float* __restrict__ out)
{
    bool ok = true;
    #pragma unroll
    for (int i = 0; i < K_FIX; ++i) ok = ok && (dp[i] == i);
    if (!ok) return;

    const int lane = (int)threadIdx.x & 63;
    const int gw   = (int)blockIdx.x * 4 + ((int)threadIdx.x >> 6);
    const int cgi  = gw % NCG;        // block's 4 waves: adjacent col groups,
    const int rgi  = gw / NCG;        // same rows (4 | 96 -> never straddles)
    const int cg0  = cgi * CG;
    const int b0   = rgi * 32;
    const int j    = lane & 31;       // col within group / B col / A row
    const int hi   = lane >> 5;

    // ---- A tile: 8 independent float4 loads (row-contiguous per lane).
    // kbase multiple of 8, N_DIM multiple of 8 -> 16B-aligned, no wrap inside
    // a segment.  Issue these before the B loads' consumers to maximize MLP.
    const int kbase = cg0 - 32 + hi * 8;
    const float* xr = x + (size_t)(b0 + j) * N_DIM;

    float4 la[4][2];
    #pragma unroll
    for (int step = 0; step < 4; ++step) {
        int c = kbase + 16 * step;
        if (c < 0) c += N_DIM;
        la[step][0] = *reinterpret_cast<const float4*>(xr + c);
        la[step][1] = *reinterpret_cast<const float4*>(xr + c + 4);
    }

    // ---- B fragments: 4 coalesced 16B loads from table (or inline build) ---
    short8v Bf[4];
    if (USE_TAB) {
        const short8v* bt = btab + (size_t)cgi * 4 * 64 + lane;
        #pragma unroll
        for (int step = 0; step < 4; ++step)
            Bf[step] = bt[(size_t)step * 64];
    } else {
        #pragma unroll
        for (int step = 0; step < 4; ++step)
            Bf[step] = build_bfrag(V, cg0, j, hi, step);
    }

    f32x16 acc = {0.f,0.f,0.f,0.f, 0.f,0.f,0.f,0.f,
                  0.f,0.f,0.f,0.f, 0.f,0.f,0.f,0.f};
    #pragma unroll
    for (int step = 0; step < 4; ++step) {
        const short8v a = pack8(la[step][0], la[step][1]);
        acc = __builtin_amdgcn_mfma_f32_32x32x16_bf16(a, Bf[step], acc, 0, 0, 0);
    }

    // ---- store: col = j, row = (reg&3) + 8*(reg>>2) + 4*hi ----
    float* ob = out + (size_t)b0 * N_DIM + cg0 + j;
    #pragma unroll
    for (int reg = 0; reg < 16; ++reg) {
        const int row = (reg & 3) + 8 * (reg >> 2) + 4 * hi;
        ob[(size_t)row * N_DIM] = acc[reg];
    }
}

// ---------------- Path 2: general K=30 (arbitrary diag values) --------------
#define G_NBT   128
#define G_BROWS (BATCH_N / G_NBT)    // 64

__global__ __launch_bounds__(256)
void fc_diag_general30(const float* __restrict__ x, const float* __restrict__ V,
                       const int* __restrict__ dp, float* __restrict__ out)
{
    bool contig = true;
    #pragma unroll
    for (int i = 0; i < K_FIX; ++i) contig = contig && (dp[i] == i);
    if (contig) return;  // fast kernel handled it

    const int NRT2 = N_DIM / 256;
    const int rtile = blockIdx.x % NRT2;
    const int btile = blockIdx.x / NRT2;
    const int r  = rtile * 256 + (int)threadIdx.x;
    const int b0 = btile * G_BROWS;

    int   CI[K_FIX];
    float VW[K_FIX];
    #pragma unroll
    for (int i = 0; i < K_FIX; ++i) {
        int d = dp[i] % N_DIM; if (d < 0) d += N_DIM;
        int c = r - d; if (c < 0) c += N_DIM;
        CI[i] = c;
        VW[i] = V[(size_t)d * N_DIM + c];
    }

    for (int b = b0; b < b0 + G_BROWS; b += 2) {
        const float* xb0 = x + (size_t)b * N_DIM;
        const float* xb1 = xb0 + N_DIM;
        float a0 = 0.f, a1 = 0.f;
        #pragma unroll
        for (int i = 0; i < K_FIX; ++i) {
            const float w = VW[i]; const int c = CI[i];
            a0 = fmaf(xb0[c], w, a0);
            a1 = fmaf(xb1[c], w, a1);
        }
        out[(size_t)b * N_DIM + r]       = a0;
        out[(size_t)(b + 1) * N_DIM + r] = a1;
    }
}

// ---------------- Path 3: naive fallback for K != 30 ------------------------
__global__ void fc_diag_naive(const float* __restrict__ x, const float* __restrict__ V,
                              const int* __restrict__ dp, int K, float* __restrict__ out)
{
    size_t idx   = (size_t)blockIdx.x * blockDim.x + threadIdx.x;
    size_t total = (size_t)BATCH_N * N_DIM;
    size_t step  = (size_t)gridDim.x * blockDim.x;
    for (; idx < total; idx += step) {
        int b = (int)(idx / N_DIM), r = (int)(idx % N_DIM);
        float acc = 0.f;
        for (int i = 0; i < K; ++i) {
            int d = dp[i] % N_DIM; if (d < 0) d += N_DIM;
            int c = r - d; if (c < 0) c += N_DIM;
            acc = fmaf(x[(size_t)b * N_DIM + c], V[(size_t)d * N_DIM + c], acc);
        }
        out[idx] = acc;
    }
}

extern "C" void kernel_launch(void* const* d_in, const int* in_sizes, int n_in,
                              void* d_out, int out_size, void* d_ws, size_t ws_size,
                              hipStream_t stream)
{
    const float* x  = (const float*)d_in[0];
    const float* V  = (const float*)d_in[1];
    const int*   dp = (const int*)d_in[2];
    float* out = (float*)d_out;
    const int K = in_sizes[2];

    if (K == K_FIX) {
        if (ws_size >= BTAB_BYTES) {
            short8v* btab = (short8v*)d_ws;
            build_btab<<<dim3(NCG), dim3(64), 0, stream>>>(V, dp, btab);
            fc_diag_mfma32<true><<<dim3(NCG * NRG / 4), dim3(256), 0, stream>>>(
                x, V, dp, btab, out);
        } else {
            fc_diag_mfma32<false><<<dim3(NCG * NRG / 4), dim3(256), 0, stream>>>(
                x, V, dp, nullptr, out);
        }
        fc_diag_general30<<<dim3((N_DIM / 256) * G_NBT), dim3(256), 0, stream>>>(x, V, dp, out);
    } else {
        fc_diag_naive<<<dim3(2048), dim3(256), 0, stream>>>(x, V, dp, K, out);
    }
}

// Round 10
// 51.811 us; speedup vs baseline: 1.7215x; 1.0439x over previous
//
#include <hip/hip_runtime.h>
#include <hip/hip_bf16.h>

#define N_DIM   3072
#define BATCH_N 8192
#define K_FIX   30

typedef __attribute__((ext_vector_type(8)))  short short8v;   // 8 bf16
typedef __attribute__((ext_vector_type(16))) float f32x16;

#define CG     32
#define NCG    (N_DIM / CG)          // 96 col groups
#define NRG    (BATCH_N / 32)        // 256 row groups (32 rows per wave)
#define BTAB_BYTES (NCG * 4 * 64 * sizeof(short8v))   // 393,216 B

static __device__ __forceinline__ short bfs(float f) {
    __hip_bfloat16 h = __float2bfloat16(f);       // RNE; compiler pairs into
    return __builtin_bit_cast(short, h);          // v_cvt_pk_bf16_f32 (m240)
}

static __device__ __forceinline__ short8v pack8(const float4 a, const float4 b) {
    short8v r;
    r[0] = bfs(a.x); r[1] = bfs(a.y); r[2] = bfs(a.z); r[3] = bfs(a.w);
    r[4] = bfs(b.x); r[5] = bfs(b.y); r[6] = bfs(b.z); r[7] = bfs(b.w);
    return r;
}

// ---- B-fragment build (band of W^T), shared by pre-kernel and fallback ----
// Bf[step][jj]: k = 16*step + hi*8 + jj, i = j + 32 - k, B = V[i][cg0-32+k].
static __device__ __forceinline__ short8v build_bfrag(
    const float* __restrict__ V, int cg0, int j, int hi, int step)
{
    short8v v8;
    #pragma unroll
    for (int jj = 0; jj < 8; ++jj) {
        const int k = 16 * step + hi * 8 + jj;
        const int i = j + 32 - k;
        short v = 0;
        if (i >= 0 && i < K_FIX) {
            int c = cg0 - 32 + k;
            if (c < 0) c += N_DIM;
            v = bfs(V[(size_t)i * N_DIM + c]);
        }
        v8[jj] = v;
    }
    return v8;
}

// ---------------- pre-kernel: materialize B-fragment table into d_ws --------
__global__ __launch_bounds__(64)
void build_btab(const float* __restrict__ V, const int* __restrict__ dp,
                short8v* __restrict__ btab)
{
    bool ok = true;
    #pragma unroll
    for (int i = 0; i < K_FIX; ++i) ok = ok && (dp[i] == i);
    if (!ok) return;

    const int cgi  = (int)blockIdx.x;
    const int lane = (int)threadIdx.x;
    const int j    = lane & 31;
    const int hi   = lane >> 5;
    const int cg0  = cgi * CG;
    #pragma unroll
    for (int step = 0; step < 4; ++step)
        btab[(cgi * 4 + step) * 64 + lane] = build_bfrag(V, cg0, j, hi, step);
}

// ---------------- Path 1: coalesced-stage barrier-free MFMA band-GEMM -------
// ONE 32x32 tile per wave (24576 waves, TLP-hidden latency, no barriers).
// R9 diagnosis: direct A-frag loads are lane-scattered over 32 rows (~64
// cache lines PER INSTRUCTION, ~768 line-events/wave) -> L1/TA front-end
// saturates while HBM/VALU/MFMA idle.  Fix: stage the 32x64 f32 x-tile in
// WAVE-PRIVATE LDS with 8 fully-coalesced loads (lane-contiguous 256B runs),
// slot-XOR swizzle (slot ^= row&15) for near-conflict-free ds_write_b128 /
// ds_read_b128, then read A-frags from LDS.  Same-wave LDS dep -> only
// lgkmcnt waits, NO __syncthreads.  B from btab (R9).
// C/D layout (m74/m101): col = lane&31, row = (reg&3)+8*(reg>>2)+4*(lane>>5).
template<bool USE_TAB>
__global__ __launch_bounds__(256)
void fc_diag_mfma32(const float* __restrict__ x, const float* __restrict__ V,
                    const int* __restrict__ dp, const short8v* __restrict__ btab,
                    float* __restrict__ out)
{
    bool ok = true;
    #pragma unroll
    for (int i = 0; i < K_FIX; ++i) ok = ok && (dp[i] == i);
    if (!ok) return;

    __shared__ float Xs[4][32 * 64];     // 8 KB per wave, 32 KB per block

    const int lane = (int)threadIdx.x & 63;
    const int wv   = (int)threadIdx.x >> 6;
    const int gw   = (int)blockIdx.x * 4 + wv;
    const int cgi  = gw % NCG;        // block's 4 waves: adjacent col groups,
    const int rgi  = gw / NCG;        // same rows (4 | 96 -> never straddles)
    const int cg0  = cgi * CG;
    const int b0   = rgi * 32;
    const int j    = lane & 31;       // col within group / B col / A row
    const int hi   = lane >> 5;
    float* xw = &Xs[wv][0];

    // ---- stage x tile: rows b0..b0+31, cols [cg0-32, cg0+32), f32 ----
    // idx = u*64+lane: row = idx>>4 (4 rows/instr), slot = idx&15 (16B col
    // chunk).  Lane-contiguous 256B per row -> ~8 lines/instr (vs 64 in R9).
    // LDS addr: row*64 + (slot ^ (row&15))*4 floats.
    #pragma unroll
    for (int u = 0; u < 8; ++u) {
        const int idx  = u * 64 + lane;
        const int row  = idx >> 4;
        const int slot = idx & 15;
        int c = cg0 - 32 + slot * 4;
        if (c < 0) c += N_DIM;
        const float4 v = *reinterpret_cast<const float4*>(
            x + (size_t)(b0 + row) * N_DIM + c);
        *reinterpret_cast<float4*>(xw + row * 64 + ((slot ^ (row & 15)) << 2)) = v;
    }

    // ---- B fragments: 4 coalesced 16B loads from table (or inline build) ---
    short8v Bf[4];
    if (USE_TAB) {
        const short8v* bt = btab + (size_t)cgi * 4 * 64 + lane;
        #pragma unroll
        for (int step = 0; step < 4; ++step)
            Bf[step] = bt[(size_t)step * 64];
    } else {
        #pragma unroll
        for (int step = 0; step < 4; ++step)
            Bf[step] = build_bfrag(V, cg0, j, hi, step);
    }

    // ---- A frags from LDS (swizzled ds_read_b128) + MFMA ----
    // Lane needs row j, float cols hi*8 + 16*step .. +8  -> slots
    // hi*2 + 4*step + {0,1}, XORed with j&15.
    f32x16 acc = {0.f,0.f,0.f,0.f, 0.f,0.f,0.f,0.f,
                  0.f,0.f,0.f,0.f, 0.f,0.f,0.f,0.f};
    #pragma unroll
    for (int step = 0; step < 4; ++step) {
        const int s0 = (hi * 2 + 4 * step + 0) ^ (j & 15);
        const int s1 = (hi * 2 + 4 * step + 1) ^ (j & 15);
        const float4 h0 = *reinterpret_cast<const float4*>(xw + j * 64 + (s0 << 2));
        const float4 h1 = *reinterpret_cast<const float4*>(xw + j * 64 + (s1 << 2));
        acc = __builtin_amdgcn_mfma_f32_32x32x16_bf16(pack8(h0, h1), Bf[step],
                                                      acc, 0, 0, 0);
    }

    // ---- store: col = j, row = (reg&3) + 8*(reg>>2) + 4*hi ----
    float* ob = out + (size_t)b0 * N_DIM + cg0 + j;
    #pragma unroll
    for (int reg = 0; reg < 16; ++reg) {
        const int row = (reg & 3) + 8 * (reg >> 2) + 4 * hi;
        ob[(size_t)row * N_DIM] = acc[reg];
    }
}

// ---------------- Path 2: general K=30 (arbitrary diag values) --------------
#define G_NBT   128
#define G_BROWS (BATCH_N / G_NBT)    // 64

__global__ __launch_bounds__(256)
void fc_diag_general30(const float* __restrict__ x, const float* __restrict__ V,
                       const int* __restrict__ dp, float* __restrict__ out)
{
    bool contig = true;
    #pragma unroll
    for (int i = 0; i < K_FIX; ++i) contig = contig && (dp[i] == i);
    if (contig) return;  // fast kernel handled it

    const int NRT2 = N_DIM / 256;
    const int rtile = blockIdx.x % NRT2;
    const int btile = blockIdx.x / NRT2;
    const int r  = rtile * 256 + (int)threadIdx.x;
    const int b0 = btile * G_BROWS;

    int   CI[K_FIX];
    float VW[K_FIX];
    #pragma unroll
    for (int i = 0; i < K_FIX; ++i) {
        int d = dp[i] % N_DIM; if (d < 0) d += N_DIM;
        int c = r - d; if (c < 0) c += N_DIM;
        CI[i] = c;
        VW[i] = V[(size_t)d * N_DIM + c];
    }

    for (int b = b0; b < b0 + G_BROWS; b += 2) {
        const float* xb0 = x + (size_t)b * N_DIM;
        const float* xb1 = xb0 + N_DIM;
        float a0 = 0.f, a1 = 0.f;
        #pragma unroll
        for (int i = 0; i < K_FIX; ++i) {
            const float w = VW[i]; const int c = CI[i];
            a0 = fmaf(xb0[c], w, a0);
            a1 = fmaf(xb1[c], w, a1);
        }
        out[(size_t)b * N_DIM + r]       = a0;
        out[(size_t)(b + 1) * N_DIM + r] = a1;
    }
}

// ---------------- Path 3: naive fallback for K != 30 ------------------------
__global__ void fc_diag_naive(const float* __restrict__ x, const float* __restrict__ V,
                              const int* __restrict__ dp, int K, float* __restrict__ out)
{
    size_t idx   = (size_t)blockIdx.x * blockDim.x + threadIdx.x;
    size_t total = (size_t)BATCH_N * N_DIM;
    size_t step  = (size_t)gridDim.x * blockDim.x;
    for (; idx < total; idx += step) {
        int b = (int)(idx / N_DIM), r = (int)(idx % N_DIM);
        float acc = 0.f;
        for (int i = 0; i < K; ++i) {
            int d = dp[i] % N_DIM; if (d < 0) d += N_DIM;
            int c = r - d; if (c < 0) c += N_DIM;
            acc = fmaf(x[(size_t)b * N_DIM + c], V[(size_t)d * N_DIM + c], acc);
        }
        out[idx] = acc;
    }
}

extern "C" void kernel_launch(void* const* d_in, const int* in_sizes, int n_in,
                              void* d_out, int out_size, void* d_ws, size_t ws_size,
                              hipStream_t stream)
{
    const float* x  = (const float*)d_in[0];
    const float* V  = (const float*)d_in[1];
    const int*   dp = (const int*)d_in[2];
    float* out = (float*)d_out;
    const int K = in_sizes[2];

    if (K == K_FIX) {
        if (ws_size >= BTAB_BYTES) {
            short8v* btab = (short8v*)d_ws;
            build_btab<<<dim3(NCG), dim3(64), 0, stream>>>(V, dp, btab);
            fc_diag_mfma32<true><<<dim3(NCG * NRG / 4), dim3(256), 0, stream>>>(
                x, V, dp, btab, out);
        } else {
            fc_diag_mfma32<false><<<dim3(NCG * NRG / 4), dim3(256), 0, stream>>>(
                x, V, dp, nullptr, out);
        }
        fc_diag_general30<<<dim3((N_DIM / 256) * G_NBT), dim3(256), 0, stream>>>(x, V, dp, out);
    } else {
        fc_diag_naive<<<dim3(2048), dim3(256), 0, stream>>>(x, V, dp, K, out);
    }
}

// Round 11
// 49.672 us; speedup vs baseline: 1.7956x; 1.0431x over previous
//
#include <hip/hip_runtime.h>
#include <hip/hip_bf16.h>

#define N_DIM   3072
#define BATCH_N 8192
#define K_FIX   30

typedef __attribute__((ext_vector_type(8)))  short short8v;   // 8 bf16
typedef __attribute__((ext_vector_type(16))) float f32x16;

#define CG     32
#define NCG    (N_DIM / CG)          // 96 col groups
#define BCOLS  256                   // out cols per block (8 waves)
#define NCT    (N_DIM / BCOLS)       // 12 col tiles
#define NRG    (BATCH_N / 32)        // 256 row groups
#define TGRAN  72                    // staged 16B-granules per row (288 cols)
#define PGRAN  80                    // padded LDS row stride in granules
#define BTAB_BYTES (NCG * 4 * 64 * sizeof(short8v))   // 393,216 B

static __device__ __forceinline__ short bfs(float f) {
    __hip_bfloat16 h = __float2bfloat16(f);       // RNE; compiler pairs into
    return __builtin_bit_cast(short, h);          // v_cvt_pk_bf16_f32 (m240)
}

static __device__ __forceinline__ short8v pack8(const float4 a, const float4 b) {
    short8v r;
    r[0] = bfs(a.x); r[1] = bfs(a.y); r[2] = bfs(a.z); r[3] = bfs(a.w);
    r[4] = bfs(b.x); r[5] = bfs(b.y); r[6] = bfs(b.z); r[7] = bfs(b.w);
    return r;
}

// ---- B-fragment build (band of W^T) ----
// Bf[step][jj]: k = 16*step + hi*8 + jj, i = j + 32 - k, B = V[i][cg0-32+k].
static __device__ __forceinline__ short8v build_bfrag(
    const float* __restrict__ V, int cg0, int j, int hi, int step)
{
    short8v v8;
    #pragma unroll
    for (int jj = 0; jj < 8; ++jj) {
        const int k = 16 * step + hi * 8 + jj;
        const int i = j + 32 - k;
        short v = 0;
        if (i >= 0 && i < K_FIX) {
            int c = cg0 - 32 + k;
            if (c < 0) c += N_DIM;
            v = bfs(V[(size_t)i * N_DIM + c]);
        }
        v8[jj] = v;
    }
    return v8;
}

// ---------------- pre-kernel: materialize B-fragment table into d_ws --------
__global__ __launch_bounds__(64)
void build_btab(const float* __restrict__ V, const int* __restrict__ dp,
                short8v* __restrict__ btab)
{
    bool ok = true;
    #pragma unroll
    for (int i = 0; i < K_FIX; ++i) ok = ok && (dp[i] == i);
    if (!ok) return;

    const int cgi  = (int)blockIdx.x;
    const int lane = (int)threadIdx.x;
    const int j    = lane & 31;
    const int hi   = lane >> 5;
    const int cg0  = cgi * CG;
    #pragma unroll
    for (int step = 0; step < 4; ++step)
        btab[(cgi * 4 + step) * 64 + lane] = build_bfrag(V, cg0, j, hi, step);
}

// ---------------- Path 1: block-cooperative MFMA band-GEMM ------------------
// 512-thread block stages ONE 32-row x 288-col f32 x tile (cols [C0-32,
// C0+256), 1.125x overlap vs R10's per-wave 2x), one barrier, then 8 waves
// each compute a 32x32 output tile: D = A[32x64] x B[64x32] via 4 x
// mfma_f32_32x32x16_bf16 with A-frags read from the swizzled LDS tile
// (R10's verified conflict-free pattern: granule ^= row&15, row stride 80
// granules) and B from btab.  LDS 40 KB -> 4 blocks/CU = 32 waves/CU (max).
// C/D layout (m74/m101): col = lane&31, row = (reg&3)+8*(reg>>2)+4*(lane>>5).
template<bool USE_TAB>
__global__ __launch_bounds__(512)
void fc_diag_mfma32(const float* __restrict__ x, const float* __restrict__ V,
                    const int* __restrict__ dp, const short8v* __restrict__ btab,
                    float* __restrict__ out)
{
    bool ok = true;
    #pragma unroll
    for (int i = 0; i < K_FIX; ++i) ok = ok && (dp[i] == i);
    if (!ok) return;                 // block-uniform: safe w.r.t. barrier

    __shared__ float Xs[32 * PGRAN * 4];     // 40,960 B

    const int tid   = (int)threadIdx.x;
    const int lane  = tid & 63;
    const int wv    = tid >> 6;              // 8 waves
    const int ctile = (int)blockIdx.x % NCT;
    const int rtile = (int)blockIdx.x / NCT;
    const int C0 = ctile * BCOLS;
    const int b0 = rtile * 32;
    const int cgi = ctile * 8 + wv;          // this wave's 32-col group
    const int j    = lane & 31;              // out col within group / A row
    const int hi   = lane >> 5;

    // ---- B fragments: 4 coalesced 16B loads (independent of staging) ----
    short8v Bf[4];
    if (USE_TAB) {
        const short8v* bt = btab + (size_t)cgi * 4 * 64 + lane;
        #pragma unroll
        for (int step = 0; step < 4; ++step)
            Bf[step] = bt[(size_t)step * 64];
    } else {
        #pragma unroll
        for (int step = 0; step < 4; ++step)
            Bf[step] = build_bfrag(V, cgi * CG, j, hi, step);
    }

    // ---- cooperative stage: rows b0..b0+31, cols [C0-32, C0+256) ----
    // 2304 granules / 512 threads = 4.5 -> 5 iters.  Consecutive lanes =
    // consecutive granules of one x row (~1KB runs, ~8 lines/instr).
    // LDS granule addr: row*80 + (slot ^ (row&15))  (slot<=71 -> ^15 <= 79).
    #pragma unroll
    for (int u = 0; u < 5; ++u) {
        const int idx = tid + u * 512;
        if (idx < 32 * TGRAN) {
            const int row  = idx / TGRAN;
            const int slot = idx - row * TGRAN;
            int c = C0 - 32 + slot * 4;
            if (c < 0) c += N_DIM;           // only ctile==0, slot<8
            const float4 v = *reinterpret_cast<const float4*>(
                x + (size_t)(b0 + row) * N_DIM + c);
            *reinterpret_cast<float4*>(
                &Xs[(row * PGRAN + (slot ^ (row & 15))) * 4]) = v;
        }
    }
    __syncthreads();

    // ---- A frags from LDS + MFMA ----
    // Wave wv needs tile granules wv*8 + hi*2 + 4*step + {0,1} of row j.
    f32x16 acc = {0.f,0.f,0.f,0.f, 0.f,0.f,0.f,0.f,
                  0.f,0.f,0.f,0.f, 0.f,0.f,0.f,0.f};
    const int gb = wv * 8 + hi * 2;
    #pragma unroll
    for (int step = 0; step < 4; ++step) {
        const int g0 = (gb + 4 * step + 0) ^ (j & 15);
        const int g1 = (gb + 4 * step + 1) ^ (j & 15);
        const float4 h0 = *reinterpret_cast<const float4*>(&Xs[(j * PGRAN + g0) * 4]);
        const float4 h1 = *reinterpret_cast<const float4*>(&Xs[(j * PGRAN + g1) * 4]);
        acc = __builtin_amdgcn_mfma_f32_32x32x16_bf16(pack8(h0, h1), Bf[step],
                                                      acc, 0, 0, 0);
    }

    // ---- store: col = j, row = (reg&3) + 8*(reg>>2) + 4*hi ----
    float* ob = out + (size_t)b0 * N_DIM + C0 + wv * 32 + j;
    #pragma unroll
    for (int reg = 0; reg < 16; ++reg) {
        const int row = (reg & 3) + 8 * (reg >> 2) + 4 * hi;
        ob[(size_t)row * N_DIM] = acc[reg];
    }
}

// ---------------- Path 2: general K=30 (arbitrary diag values) --------------
#define G_NBT   128
#define G_BROWS (BATCH_N / G_NBT)    // 64

__global__ __launch_bounds__(256)
void fc_diag_general30(const float* __restrict__ x, const float* __restrict__ V,
                       const int* __restrict__ dp, float* __restrict__ out)
{
    bool contig = true;
    #pragma unroll
    for (int i = 0; i < K_FIX; ++i) contig = contig && (dp[i] == i);
    if (contig) return;  // fast kernel handled it

    const int NRT2 = N_DIM / 256;
    const int rtile = blockIdx.x % NRT2;
    const int btile = blockIdx.x / NRT2;
    const int r  = rtile * 256 + (int)threadIdx.x;
    const int b0 = btile * G_BROWS;

    int   CI[K_FIX];
    float VW[K_FIX];
    #pragma unroll
    for (int i = 0; i < K_FIX; ++i) {
        int d = dp[i] % N_DIM; if (d < 0) d += N_DIM;
        int c = r - d; if (c < 0) c += N_DIM;
        CI[i] = c;
        VW[i] = V[(size_t)d * N_DIM + c];
    }

    for (int b = b0; b < b0 + G_BROWS; b += 2) {
        const float* xb0 = x + (size_t)b * N_DIM;
        const float* xb1 = xb0 + N_DIM;
        float a0 = 0.f, a1 = 0.f;
        #pragma unroll
        for (int i = 0; i < K_FIX; ++i) {
            const float w = VW[i]; const int c = CI[i];
            a0 = fmaf(xb0[c], w, a0);
            a1 = fmaf(xb1[c], w, a1);
        }
        out[(size_t)b * N_DIM + r]       = a0;
        out[(size_t)(b + 1) * N_DIM + r] = a1;
    }
}

// ---------------- Path 3: naive fallback for K != 30 ------------------------
__global__ void fc_diag_naive(const float* __restrict__ x, const float* __restrict__ V,
                              const int* __restrict__ dp, int K, float* __restrict__ out)
{
    size_t idx   = (size_t)blockIdx.x * blockDim.x + threadIdx.x;
    size_t total = (size_t)BATCH_N * N_DIM;
    size_t step  = (size_t)gridDim.x * blockDim.x;
    for (; idx < total; idx += step) {
        int b = (int)(idx / N_DIM), r = (int)(idx % N_DIM);
        float acc = 0.f;
        for (int i = 0; i < K; ++i) {
            int d = dp[i] % N_DIM; if (d < 0) d += N_DIM;
            int c = r - d; if (c < 0) c += N_DIM;
            acc = fmaf(x[(size_t)b * N_DIM + c], V[(size_t)d * N_DIM + c], acc);
        }
        out[idx] = acc;
    }
}

extern "C" void kernel_launch(void* const* d_in, const int* in_sizes, int n_in,
                              void* d_out, int out_size, void* d_ws, size_t ws_size,
                              hipStream_t stream)
{
    const float* x  = (const float*)d_in[0];
    const float* V  = (const float*)d_in[1];
    const int*   dp = (const int*)d_in[2];
    float* out = (float*)d_out;
    const int K = in_sizes[2];

    if (K == K_FIX) {
        if (ws_size >= BTAB_BYTES) {
            short8v* btab = (short8v*)d_ws;
            build_btab<<<dim3(NCG), dim3(64), 0, stream>>>(V, dp, btab);
            fc_diag_mfma32<true><<<dim3(NCT * NRG), dim3(512), 0, stream>>>(
                x, V, dp, btab, out);
        } else {
            fc_diag_mfma32<false><<<dim3(NCT * NRG), dim3(512), 0, stream>>>(
                x, V, dp, nullptr, out);
        }
        fc_diag_general30<<<dim3((N_DIM / 256) * G_NBT), dim3(256), 0, stream>>>(x, V, dp, out);
    } else {
        fc_diag_naive<<<dim3(2048), dim3(256), 0, stream>>>(x, V, dp, K, out);
    }
}